// Round 12
// baseline (469.226 us; speedup 1.0000x reference)
//
#include <hip/hip_runtime.h>
#include <hip/hip_bf16.h>
#include <math.h>

#define B_   256
#define L_   196
#define ENC_ 2048
#define DEC_ 512
#define HID_ 512

typedef __attribute__((ext_vector_type(8))) short short8v;
typedef __attribute__((ext_vector_type(4))) short short4v;
typedef __attribute__((ext_vector_type(4))) float f32x4;

static __device__ __forceinline__ short f2bf(float x) {
    unsigned u = __float_as_uint(x);
    u += 0x7fffu + ((u >> 16) & 1u);   // round-to-nearest-even
    return (short)(u >> 16);
}

// ---------------------------------------------------------------------------
// Wf (f32 [512,2048]) -> bf16, PRE-SWIZZLED for BK=32 tiles (v6 layout):
// within each 64B (4-unit) K-tile segment of row n,
// physical unit = logical ^ ((n>>1)&3).   2-way max bank aliasing (free).
// ---------------------------------------------------------------------------
__global__ __launch_bounds__(256) void kconvert(const float* __restrict__ Wf,
                                                short* __restrict__ wfbf) {
    int idx = (blockIdx.x * 256 + threadIdx.x) * 4;   // over 512*2048 = 1M elems
    int n  = idx >> 11;
    int e0 = idx & 2047;
    float4 f = *(const float4*)(Wf + idx);
    short4v h;
    h.x = f2bf(f.x); h.y = f2bf(f.y); h.z = f2bf(f.z); h.w = f2bf(f.w);
    int tile = e0 >> 5;                      // 32-elem K-tile within row
    int lu   = (e0 >> 3) & 3;                // logical 8-elem unit in tile
    int pu   = lu ^ ((n >> 1) & 3);          // physical unit (swizzled)
    int off  = n * 2048 + tile * 32 + pu * 8 + (e0 & 7);
    *(short4v*)(wfbf + off) = h;
}

// ---------------------------------------------------------------------------
// hid_emb[b,h] = hidden[b,:] . Wh[h,:] + bh[h]     (256x512, K=512, fp32)
// ---------------------------------------------------------------------------
__global__ __launch_bounds__(512) void khid(const float* __restrict__ hidden,
                                            const float* __restrict__ Wh,
                                            const float* __restrict__ bh,
                                            float* __restrict__ hid_emb) {
    __shared__ float hs[8][512];
    int t = threadIdx.x;
    int bg = blockIdx.x * 8;
    #pragma unroll
    for (int i = 0; i < 8; ++i) hs[i][t] = hidden[(size_t)(bg + i) * 512 + t];
    __syncthreads();
    float acc[8] = {0.f,0.f,0.f,0.f,0.f,0.f,0.f,0.f};
    const float4* wrow = (const float4*)(Wh + (size_t)t * 512);
    #pragma unroll 4
    for (int d4 = 0; d4 < 128; ++d4) {
        float4 w = wrow[d4];
        int d = d4 * 4;
        #pragma unroll
        for (int i = 0; i < 8; ++i)
            acc[i] += w.x * hs[i][d] + w.y * hs[i][d+1] + w.z * hs[i][d+2] + w.w * hs[i][d+3];
    }
    float bhv = bh[t];
    #pragma unroll
    for (int i = 0; i < 8; ++i)
        hid_emb[(size_t)(bg + i) * 512 + t] = acc[i] + bhv;
}

// ---------------------------------------------------------------------------
// Fused score GEMM v9: 64M x 512N tile, BK=32, 512 threads / 8 waves.
// Wave grid 2m x 4n: wave = 32 rows x 128 cols, acc[2][8].
// A NEVER TOUCHES LDS: lane (c,g) loads its MFMA A-fragment (8 floats at
// feat[row=...+c][k0+g*8]) directly global->reg as 2x float4, converts to
// bf16 in registers.  Kills the per-iter convert->ds_write->lgkm serial
// chain that bounded v3..v8.  B path is v6-verbatim (gload_lds from
// pre-swizzled wfbf into 2x32KB dbuf).  Barrier orders ONLY B:
// s_waitcnt vmcnt(4) lgkmcnt(0) -- A(k+2) rides across.  LDS 65 KB ->
// 2 blocks/CU (the proven-binding factor).  MFMA operand mapping identical
// to v6's LDS reads => bit-identical numerics.
// ---------------------------------------------------------------------------
__global__ __launch_bounds__(512, 4) void kscore(
    const float* __restrict__ feat, const short* __restrict__ wfbf,
    const float* __restrict__ bf, const float* __restrict__ hid_emb,
    const float* __restrict__ We, const float* __restrict__ be,
    float* __restrict__ score)
{
    __shared__ short lds_b[2 * 512 * 32];   // 2 x 32 KB, swizzled [n][k32]
    __shared__ float score_s[8][32];

    const int tid  = threadIdx.x;
    const int wave = tid >> 6;
    const int lane = tid & 63;
    const int g    = lane >> 4;
    const int c    = lane & 15;
    const int wr   = wave >> 2;              // 0..1 : 32-row m sub-tile
    const int wc   = wave & 3;               // 0..3 : 128-col n sub-tile
    const int m0   = blockIdx.x * 64;

    // A direct-load bases: frag mi -> row m0 + wr*32 + mi*16 + c, k = g*8..
    const float* gA0 = feat + (size_t)(m0 + wr * 32 + c) * ENC_ + g * 8;
    const float* gA1 = gA0 + (size_t)16 * ENC_;

    f32x4 acc[2][8];
    #pragma unroll
    for (int i = 0; i < 2; ++i)
        #pragma unroll
        for (int j = 0; j < 8; ++j)
            acc[i][j] = (f32x4)0.f;

    short8v af0, af1;
    float4 a00, a01, a10, a11;               // next A-tile, fp32

#define STAGE_B(K0, BUF)                                                      \
    {                                                                         \
        short* bbase = lds_b + (size_t)(BUF) * 16384;                         \
        _Pragma("unroll")                                                     \
        for (int j = 0; j < 4; ++j) {                                         \
            int ubase = j * 512 + wave * 64;       /* wave-uniform base */    \
            int ulin  = ubase + lane;              /* 2048 units total  */    \
            int n = ulin >> 2, u = ulin & 3;                                  \
            const short* gp = wfbf + (size_t)n * ENC_ + (K0) + u * 8;         \
            short* lp = bbase + (size_t)ubase * 8;                            \
            __builtin_amdgcn_global_load_lds(                                 \
                (const __attribute__((address_space(1))) void*)gp,            \
                (__attribute__((address_space(3))) void*)lp, 16, 0, 0);       \
        }                                                                     \
    }

#define LOAD_A(KT)                                                            \
    {                                                                         \
        const float* p0 = gA0 + (KT) * 32;                                    \
        const float* p1 = gA1 + (KT) * 32;                                    \
        a00 = *(const float4*)(p0);  a01 = *(const float4*)(p0 + 4);          \
        a10 = *(const float4*)(p1);  a11 = *(const float4*)(p1 + 4);          \
    }

#define CONV_A                                                                \
    {                                                                         \
        short8v t0, t1;                                                       \
        t0[0]=f2bf(a00.x); t0[1]=f2bf(a00.y); t0[2]=f2bf(a00.z);              \
        t0[3]=f2bf(a00.w); t0[4]=f2bf(a01.x); t0[5]=f2bf(a01.y);              \
        t0[6]=f2bf(a01.z); t0[7]=f2bf(a01.w);                                 \
        t1[0]=f2bf(a10.x); t1[1]=f2bf(a10.y); t1[2]=f2bf(a10.z);              \
        t1[3]=f2bf(a10.w); t1[4]=f2bf(a11.x); t1[5]=f2bf(a11.y);              \
        t1[6]=f2bf(a11.z); t1[7]=f2bf(a11.w);                                 \
        af0 = t0; af1 = t1;                                                   \
    }

#define COMPUTE_TILE(BUF)                                                     \
    {                                                                         \
        const char* lb = (const char*)lds_b + (size_t)(BUF) * 32768;          \
        _Pragma("unroll")                                                     \
        for (int nh = 0; nh < 2; ++nh) {                                      \
            short8v bq[4];                                                    \
            _Pragma("unroll")                                                 \
            for (int ni = 0; ni < 4; ++ni) {                                  \
                int n  = wc * 128 + nh * 64 + ni * 16 + c;                    \
                int un = g ^ ((n >> 1) & 3);                                  \
                bq[ni] = *(const short8v*)(lb + n * 64 + un * 16);            \
            }                                                                 \
            _Pragma("unroll")                                                 \
            for (int ni = 0; ni < 4; ++ni) {                                  \
                acc[0][nh*4+ni] = __builtin_amdgcn_mfma_f32_16x16x32_bf16(    \
                    af0, bq[ni], acc[0][nh*4+ni], 0, 0, 0);                   \
                acc[1][nh*4+ni] = __builtin_amdgcn_mfma_f32_16x16x32_bf16(    \
                    af1, bq[ni], acc[1][nh*4+ni], 0, 0, 0);                   \
            }                                                                 \
        }                                                                     \
    }

#define BAR_COUNTED(N)                                                        \
    asm volatile("s_waitcnt vmcnt(" #N ") lgkmcnt(0)" ::: "memory");          \
    __builtin_amdgcn_sched_barrier(0);                                        \
    __builtin_amdgcn_s_barrier();                                             \
    __builtin_amdgcn_sched_barrier(0);

    // ---- prologue: A(0) loads, B(0) stage, convert A(0), A(1) loads ----
    LOAD_A(0)                   // 4 vmem
    STAGE_B(0, 0)               // 4 vmem (after A in queue)
    CONV_A                      // waits A(0) -> vmcnt(4), B(0) flying
    LOAD_A(1)                   // 4 vmem
    BAR_COUNTED(4)              // retire B(0); A(1) rides across

    // ---- main loop: kt = 0..62 ----
    for (int kt = 0; kt < 63; ++kt) {
        const int buf = kt & 1;
        STAGE_B((kt + 1) * 32, buf ^ 1)      // queue: [A(k+1)4, B(k+1)4]
        COMPUTE_TILE(buf)                    // ~600 cy MFMA cover
        CONV_A                               // waits A(k+1) = vmcnt(4)
        {
            const int ka = (kt + 2 > 63) ? 63 : kt + 2;
            LOAD_A(ka)                       // A(k+2), queue tail
        }
        BAR_COUNTED(4)                       // retire B(k+1); A(k+2) flying
    }
    // ---- peel kt = 63 ----
    COMPUTE_TILE(1)

#undef STAGE_B
#undef LOAD_A
#undef CONV_A
#undef COMPUTE_TILE
#undef BAR_COUNTED

    // ---- fused epilogue: +bf +hid_emb, relu, dot We, reduce over n ----
    float wev[8], bfv[8];
    #pragma unroll
    for (int q = 0; q < 8; ++q) {
        int n = wc * 128 + (q >> 2) * 64 + (q & 3) * 16 + c;
        wev[q] = We[n];
        bfv[q] = bf[n];
    }
    #pragma unroll
    for (int mi = 0; mi < 2; ++mi) {
        float part[4] = {0.f, 0.f, 0.f, 0.f};
        #pragma unroll
        for (int j = 0; j < 4; ++j) {
            int row  = m0 + wr * 32 + mi * 16 + g * 4 + j;  // C/D row map
            int bidx = row / 196;
            const float* hrow = hid_emb + (size_t)bidx * 512;
            #pragma unroll
            for (int q = 0; q < 8; ++q) {
                int n = wc * 128 + (q >> 2) * 64 + (q & 3) * 16 + c;
                float v = acc[mi][q][j] + bfv[q] + hrow[n];
                v = fmaxf(v, 0.f);
                part[j] += v * wev[q];
            }
        }
        #pragma unroll
        for (int j = 0; j < 4; ++j) {
            float p = part[j];
            p += __shfl_xor(p, 1, 16);
            p += __shfl_xor(p, 2, 16);
            p += __shfl_xor(p, 4, 16);
            p += __shfl_xor(p, 8, 16);
            if (c == 0) score_s[wave][mi * 16 + g * 4 + j] = p;
        }
    }
    __syncthreads();
    if (tid < 64) {
        int r   = tid;
        int wrr = r >> 5;
        float s = be[0];
        #pragma unroll
        for (int wcc = 0; wcc < 4; ++wcc) s += score_s[wrr * 4 + wcc][r & 31];
        score[m0 + r] = s;
    }
}

// ---------------------------------------------------------------------------
// Softmax over L=196 + output[b,e] = sum_l w[l] * feature[b,l,e].
// ---------------------------------------------------------------------------
__global__ __launch_bounds__(256) void kout(
    const float* __restrict__ score, const float* __restrict__ feat,
    float* __restrict__ out_o, float* __restrict__ out_w)
{
    __shared__ float wbuf[196];
    __shared__ float red[8];
    int t    = threadIdx.x;
    int b    = blockIdx.x >> 1;
    int half = blockIdx.x & 1;
    int w    = t >> 6, lane = t & 63;

    float s = (t < 196) ? score[b * 196 + t] : -1e30f;
    float m = s;
    #pragma unroll
    for (int off = 32; off >= 1; off >>= 1) m = fmaxf(m, __shfl_xor(m, off, 64));
    if (lane == 0) red[w] = m;
    __syncthreads();
    m = fmaxf(fmaxf(red[0], red[1]), fmaxf(red[2], red[3]));
    float e = (t < 196) ? __expf(s - m) : 0.f;
    float sum = e;
    #pragma unroll
    for (int off = 32; off >= 1; off >>= 1) sum += __shfl_xor(sum, off, 64);
    if (lane == 0) red[4 + w] = sum;
    __syncthreads();
    sum = red[4] + red[5] + red[6] + red[7];
    float wt = e / sum;
    if (t < 196) {
        wbuf[t] = wt;
        if (half == 0) out_w[b * 196 + t] = wt;
    }
    __syncthreads();

    int e0 = half * 1024 + t * 4;
    float4 acc = make_float4(0.f, 0.f, 0.f, 0.f);
    const float* fb = feat + (size_t)b * L_ * ENC_ + e0;
    #pragma unroll 4
    for (int l = 0; l < 196; ++l) {
        float4 v = *(const float4*)(fb + (size_t)l * ENC_);
        float wl = wbuf[l];
        acc.x += wl * v.x; acc.y += wl * v.y; acc.z += wl * v.z; acc.w += wl * v.w;
    }
    *(float4*)(out_o + (size_t)b * ENC_ + e0) = acc;
}

extern "C" void kernel_launch(void* const* d_in, const int* in_sizes, int n_in,
                              void* d_out, int out_size, void* d_ws, size_t ws_size,
                              hipStream_t stream) {
    (void)in_sizes; (void)n_in; (void)out_size; (void)ws_size;
    const float* feature = (const float*)d_in[0];
    const float* hidden  = (const float*)d_in[1];
    const float* Wf      = (const float*)d_in[2];
    const float* bf      = (const float*)d_in[3];
    const float* Wh      = (const float*)d_in[4];
    const float* bh      = (const float*)d_in[5];
    const float* We      = (const float*)d_in[6];
    const float* be      = (const float*)d_in[7];

    char* ws = (char*)d_ws;
    short* wfbf    = (short*)ws;                               // 2 MB
    float* hid_emb = (float*)(ws + (2u << 20));                // 512 KB
    float* score   = (float*)(ws + (2u << 20) + (512u << 10)); // 200 KB

    float* out_o = (float*)d_out;                 // [256,2048]
    float* out_w = out_o + (size_t)B_ * ENC_;     // [256,196]

    kconvert<<<dim3(1024), dim3(256), 0, stream>>>(Wf, wfbf);
    khid<<<dim3(32), dim3(512), 0, stream>>>(hidden, Wh, bh, hid_emb);
    kscore<<<dim3(784), dim3(512), 0, stream>>>(feature, wfbf, bf, hid_emb, We, be, score);
    kout<<<dim3(512), dim3(256), 0, stream>>>(score, feature, (float*)d_out, out_w);
}

// Round 13
// 342.724 us; speedup vs baseline: 1.3691x; 1.3691x over previous
//
#include <hip/hip_runtime.h>
#include <hip/hip_bf16.h>
#include <math.h>

#define B_   256
#define L_   196
#define ENC_ 2048
#define DEC_ 512
#define HID_ 512

typedef __attribute__((ext_vector_type(8))) short short8v;
typedef __attribute__((ext_vector_type(4))) short short4v;
typedef __attribute__((ext_vector_type(4))) float f32x4;

static __device__ __forceinline__ short f2bf(float x) {
    unsigned u = __float_as_uint(x);
    u += 0x7fffu + ((u >> 16) & 1u);   // round-to-nearest-even
    return (short)(u >> 16);
}

// ---------------------------------------------------------------------------
// Wf (f32 [512,2048]) -> bf16, PRE-SWIZZLED for BK=32 tiles (v6 layout):
// within each 64B (4-unit) K-tile segment of row n,
// physical unit = logical ^ ((n>>1)&3).   2-way max bank aliasing (free).
// ---------------------------------------------------------------------------
__global__ __launch_bounds__(256) void kconvert(const float* __restrict__ Wf,
                                                short* __restrict__ wfbf) {
    int idx = (blockIdx.x * 256 + threadIdx.x) * 4;   // over 512*2048 = 1M elems
    int n  = idx >> 11;
    int e0 = idx & 2047;
    float4 f = *(const float4*)(Wf + idx);
    short4v h;
    h.x = f2bf(f.x); h.y = f2bf(f.y); h.z = f2bf(f.z); h.w = f2bf(f.w);
    int tile = e0 >> 5;                      // 32-elem K-tile within row
    int lu   = (e0 >> 3) & 3;                // logical 8-elem unit in tile
    int pu   = lu ^ ((n >> 1) & 3);          // physical unit (swizzled)
    int off  = n * 2048 + tile * 32 + pu * 8 + (e0 & 7);
    *(short4v*)(wfbf + off) = h;
}

// ---------------------------------------------------------------------------
// hid_emb[b,h] = hidden[b,:] . Wh[h,:] + bh[h]     (256x512, K=512, fp32)
// ---------------------------------------------------------------------------
__global__ __launch_bounds__(512) void khid(const float* __restrict__ hidden,
                                            const float* __restrict__ Wh,
                                            const float* __restrict__ bh,
                                            float* __restrict__ hid_emb) {
    __shared__ float hs[8][512];
    int t = threadIdx.x;
    int bg = blockIdx.x * 8;
    #pragma unroll
    for (int i = 0; i < 8; ++i) hs[i][t] = hidden[(size_t)(bg + i) * 512 + t];
    __syncthreads();
    float acc[8] = {0.f,0.f,0.f,0.f,0.f,0.f,0.f,0.f};
    const float4* wrow = (const float4*)(Wh + (size_t)t * 512);
    #pragma unroll 4
    for (int d4 = 0; d4 < 128; ++d4) {
        float4 w = wrow[d4];
        int d = d4 * 4;
        #pragma unroll
        for (int i = 0; i < 8; ++i)
            acc[i] += w.x * hs[i][d] + w.y * hs[i][d+1] + w.z * hs[i][d+2] + w.w * hs[i][d+3];
    }
    float bhv = bh[t];
    #pragma unroll
    for (int i = 0; i < 8; ++i)
        hid_emb[(size_t)(bg + i) * 512 + t] = acc[i] + bhv;
}

// ---------------------------------------------------------------------------
// Fused score GEMM v10: v6 geometry (64M x 512N, BK=32, 512 thr / 8 waves,
// wave = 64x64, acc 4x4, B dbuf 2x32KB gload_lds, A dbuf 2x4KB reg-staged,
// 74 KB LDS -> 2 blocks/CU) with the T3 PHASE-SPLIT schedule (m201 template,
// 2 phases per K-tile):
//   PHASE A: ds_read af[0..3]+bq[0..1] | issue 4x gload_lds B(k+1) +
//            1x A(k+2) load | bar | lgkm(0) | setprio(1) 8 MFMA (ni=0,1)
//   PHASE B: ds_read bq[2..3] | convert+ds_write A(k+1) | bar | lgkm(0) |
//            setprio(1) 8 MFMA (ni=2,3) | vmcnt(1) lgkm(0) | bar
// Counted vmcnt(1) at tile end retires B(k+1) only; A(k+2) rides across
// (T4).  A(k+1)'s f32 load is waited by the compiler at the convert with
// ~1.5-tile lead (no stall).  setprio arbitrates between the 2 co-resident
// blocks at unaligned phases (T5 gate).  Same MFMA order per accumulator
// as v6 => bit-identical numerics (absmax canary 1.953e-3).
// ---------------------------------------------------------------------------
__global__ __launch_bounds__(512, 4) void kscore(
    const float* __restrict__ feat, const short* __restrict__ wfbf,
    const float* __restrict__ bf, const float* __restrict__ hid_emb,
    const float* __restrict__ We, const float* __restrict__ be,
    float* __restrict__ score)
{
    __shared__ short lds_b[2 * 512 * 32];   // 2 x 32 KB, swizzled [n][k32]
    __shared__ short lds_a[2 * 64 * 32];    // 2 x  4 KB, swizzled [r][k32]
    __shared__ float score_s[8][64];

    const int tid  = threadIdx.x;
    const int wave = tid >> 6;
    const int lane = tid & 63;
    const int g    = lane >> 4;
    const int c    = lane & 15;
    const int m0   = blockIdx.x * 64;

    // ---- per-thread A staging geometry (v6-verified) ----
    const int r_a  = tid >> 3;
    const int c4   = tid & 7;
    const float* gA = feat + (size_t)(m0 + r_a) * ENC_ + c4 * 4;
    const int boffA = r_a * 64 + (((c4 >> 1) ^ ((r_a >> 1) & 3)) << 4) + (c4 & 1) * 8;

    f32x4 acc[4][4];
    #pragma unroll
    for (int i = 0; i < 4; ++i)
        #pragma unroll
        for (int j = 0; j < 4; ++j)
            acc[i][j] = (f32x4)0.f;

#define STAGE_B(K0, BUF)                                                      \
    {                                                                         \
        short* bbase = lds_b + (size_t)(BUF) * 16384;                         \
        _Pragma("unroll")                                                     \
        for (int j = 0; j < 4; ++j) {                                         \
            int ubase = j * 512 + wave * 64;       /* wave-uniform base */    \
            int ulin  = ubase + lane;              /* 2048 units total  */    \
            int n = ulin >> 2, u = ulin & 3;                                  \
            const short* gp = wfbf + (size_t)n * ENC_ + (K0) + u * 8;         \
            short* lp = bbase + (size_t)ubase * 8;                            \
            __builtin_amdgcn_global_load_lds(                                 \
                (const __attribute__((address_space(1))) void*)gp,            \
                (__attribute__((address_space(3))) void*)lp, 16, 0, 0);       \
        }                                                                     \
    }

#define RD_AF(BUF)                                                            \
    {                                                                         \
        const char* la = (const char*)lds_a + (BUF) * 4096;                   \
        _Pragma("unroll")                                                     \
        for (int mi = 0; mi < 4; ++mi) {                                      \
            int row = mi * 16 + c;                                            \
            int un  = g ^ ((row >> 1) & 3);                                   \
            af[mi] = *(const short8v*)(la + row * 64 + un * 16);              \
        }                                                                     \
    }

#define RD_BQ(BUF, N0, D0)                                                    \
    {                                                                         \
        const char* lb = (const char*)lds_b + (size_t)(BUF) * 32768;          \
        _Pragma("unroll")                                                     \
        for (int q = 0; q < 2; ++q) {                                         \
            int n  = wave * 64 + ((N0) + q) * 16 + c;                         \
            int un = g ^ ((n >> 1) & 3);                                      \
            bq[(D0) + q] = *(const short8v*)(lb + n * 64 + un * 16);          \
        }                                                                     \
    }

#define MFMA_HALF(B0, Q0)                                                     \
    __builtin_amdgcn_s_setprio(1);                                            \
    _Pragma("unroll")                                                         \
    for (int mi = 0; mi < 4; ++mi) {                                          \
        acc[mi][(B0)]   = __builtin_amdgcn_mfma_f32_16x16x32_bf16(            \
            af[mi], bq[(Q0)],   acc[mi][(B0)],   0, 0, 0);                    \
        acc[mi][(B0)+1] = __builtin_amdgcn_mfma_f32_16x16x32_bf16(            \
            af[mi], bq[(Q0)+1], acc[mi][(B0)+1], 0, 0, 0);                    \
    }                                                                         \
    __builtin_amdgcn_s_setprio(0);

#define WRITE_A(FA, BUF)                                                      \
    {                                                                         \
        short4v h0;                                                           \
        h0.x = f2bf((FA).x); h0.y = f2bf((FA).y);                             \
        h0.z = f2bf((FA).z); h0.w = f2bf((FA).w);                             \
        char* wa = (char*)lds_a + (BUF) * 4096;                               \
        *(short4v*)(wa + boffA) = h0;                                         \
    }

#define SBAR                                                                  \
    __builtin_amdgcn_sched_barrier(0);                                        \
    __builtin_amdgcn_s_barrier();                                             \
    __builtin_amdgcn_sched_barrier(0);

#define LGKM0                                                                 \
    asm volatile("s_waitcnt lgkmcnt(0)" ::: "memory");                        \
    __builtin_amdgcn_sched_barrier(0);

#define VM1_LGKM0                                                             \
    asm volatile("s_waitcnt vmcnt(1) lgkmcnt(0)" ::: "memory");               \
    __builtin_amdgcn_sched_barrier(0);

    short8v af[4], bq[4];

    // ---- prologue: B(0) staged, A(0) written, A(1) in flight ----
    STAGE_B(0, 0)
    float4 fa_cur = *(const float4*)(gA);            // A(0)
    float4 fa_nxt = *(const float4*)(gA + 32);       // A(1)
    WRITE_A(fa_cur, 0)        // compiler waits A(0) (retires B(0) too)
    fa_cur = fa_nxt;
    asm volatile("s_waitcnt lgkmcnt(0)" ::: "memory");
    SBAR                      // A(1) still in flight

    // ---- main loop: kt = 0..62, two phases per K-tile ----
    for (int kt = 0; kt < 63; ++kt) {
        const int buf = kt & 1;
        // ===== PHASE A =====
        RD_AF(buf)
        RD_BQ(buf, 0, 0)
        STAGE_B((kt + 1) * 32, buf ^ 1)              // 4 vmem
        {
            const int ka = (kt + 2 > 63) ? 63 : kt + 2;
            fa_nxt = *(const float4*)(gA + ka * 32); // 1 vmem
        }
        SBAR
        LGKM0
        MFMA_HALF(0, 0)
        SBAR
        // ===== PHASE B =====
        RD_BQ(buf, 2, 2)
        WRITE_A(fa_cur, buf ^ 1)                     // A(k+1), ~1.5-tile lead
        fa_cur = fa_nxt;
        SBAR
        LGKM0
        MFMA_HALF(2, 2)
        VM1_LGKM0                                    // retire B(k+1); A(k+2) rides
        SBAR
    }
    // ---- peel kt = 63 (buf = 1, no staging) ----
    RD_AF(1)
    RD_BQ(1, 0, 0)
    LGKM0
    MFMA_HALF(0, 0)
    RD_BQ(1, 2, 2)
    LGKM0
    MFMA_HALF(2, 2)

#undef STAGE_B
#undef RD_AF
#undef RD_BQ
#undef MFMA_HALF
#undef WRITE_A
#undef SBAR
#undef LGKM0
#undef VM1_LGKM0

    // ---- fused epilogue: +bf +hid_emb, relu, dot We, reduce over n ----
    __syncthreads();
    float wev[4], bfv[4];
    #pragma unroll
    for (int ni = 0; ni < 4; ++ni) {
        int n = wave * 64 + ni * 16 + c;
        wev[ni] = We[n];
        bfv[ni] = bf[n];
    }
    #pragma unroll
    for (int mi = 0; mi < 4; ++mi) {
        float part[4] = {0.f, 0.f, 0.f, 0.f};
        #pragma unroll
        for (int j = 0; j < 4; ++j) {
            int row  = mi * 16 + g * 4 + j;            // C/D: row=(lane>>4)*4+reg
            int bidx = (m0 + row) / 196;
            const float* hrow = hid_emb + (size_t)bidx * 512;
            #pragma unroll
            for (int ni = 0; ni < 4; ++ni) {
                int n = wave * 64 + ni * 16 + c;
                float v = acc[mi][ni][j] + bfv[ni] + hrow[n];
                v = fmaxf(v, 0.f);
                part[j] += v * wev[ni];
            }
        }
        #pragma unroll
        for (int j = 0; j < 4; ++j) {
            float p = part[j];
            p += __shfl_xor(p, 1, 16);
            p += __shfl_xor(p, 2, 16);
            p += __shfl_xor(p, 4, 16);
            p += __shfl_xor(p, 8, 16);
            if (c == 0) score_s[wave][mi * 16 + g * 4 + j] = p;
        }
    }
    __syncthreads();
    if (tid < 64) {
        float s = be[0];
        #pragma unroll
        for (int w = 0; w < 8; ++w) s += score_s[w][tid];
        score[m0 + tid] = s;
    }
}

// ---------------------------------------------------------------------------
// Softmax over L=196 + output[b,e] = sum_l w[l] * feature[b,l,e].
// ---------------------------------------------------------------------------
__global__ __launch_bounds__(256) void kout(
    const float* __restrict__ score, const float* __restrict__ feat,
    float* __restrict__ out_o, float* __restrict__ out_w)
{
    __shared__ float wbuf[196];
    __shared__ float red[8];
    int t    = threadIdx.x;
    int b    = blockIdx.x >> 1;
    int half = blockIdx.x & 1;
    int w    = t >> 6, lane = t & 63;

    float s = (t < 196) ? score[b * 196 + t] : -1e30f;
    float m = s;
    #pragma unroll
    for (int off = 32; off >= 1; off >>= 1) m = fmaxf(m, __shfl_xor(m, off, 64));
    if (lane == 0) red[w] = m;
    __syncthreads();
    m = fmaxf(fmaxf(red[0], red[1]), fmaxf(red[2], red[3]));
    float e = (t < 196) ? __expf(s - m) : 0.f;
    float sum = e;
    #pragma unroll
    for (int off = 32; off >= 1; off >>= 1) sum += __shfl_xor(sum, off, 64);
    if (lane == 0) red[4 + w] = sum;
    __syncthreads();
    sum = red[4] + red[5] + red[6] + red[7];
    float wt = e / sum;
    if (t < 196) {
        wbuf[t] = wt;
        if (half == 0) out_w[b * 196 + t] = wt;
    }
    __syncthreads();

    int e0 = half * 1024 + t * 4;
    float4 acc = make_float4(0.f, 0.f, 0.f, 0.f);
    const float* fb = feat + (size_t)b * L_ * ENC_ + e0;
    #pragma unroll 4
    for (int l = 0; l < 196; ++l) {
        float4 v = *(const float4*)(fb + (size_t)l * ENC_);
        float wl = wbuf[l];
        acc.x += wl * v.x; acc.y += wl * v.y; acc.z += wl * v.z; acc.w += wl * v.w;
    }
    *(float4*)(out_o + (size_t)b * ENC_ + e0) = acc;
}

extern "C" void kernel_launch(void* const* d_in, const int* in_sizes, int n_in,
                              void* d_out, int out_size, void* d_ws, size_t ws_size,
                              hipStream_t stream) {
    (void)in_sizes; (void)n_in; (void)out_size; (void)ws_size;
    const float* feature = (const float*)d_in[0];
    const float* hidden  = (const float*)d_in[1];
    const float* Wf      = (const float*)d_in[2];
    const float* bf      = (const float*)d_in[3];
    const float* Wh      = (const float*)d_in[4];
    const float* bh      = (const float*)d_in[5];
    const float* We      = (const float*)d_in[6];
    const float* be      = (const float*)d_in[7];

    char* ws = (char*)d_ws;
    short* wfbf    = (short*)ws;                               // 2 MB
    float* hid_emb = (float*)(ws + (2u << 20));                // 512 KB
    float* score   = (float*)(ws + (2u << 20) + (512u << 10)); // 200 KB

    float* out_o = (float*)d_out;                 // [256,2048]
    float* out_w = out_o + (size_t)B_ * ENC_;     // [256,196]

    kconvert<<<dim3(1024), dim3(256), 0, stream>>>(Wf, wfbf);
    khid<<<dim3(32), dim3(512), 0, stream>>>(hidden, Wh, bh, hid_emb);
    kscore<<<dim3(784), dim3(512), 0, stream>>>(feature, wfbf, bf, hid_emb, We, be, score);
    kout<<<dim3(512), dim3(256), 0, stream>>>(score, feature, (float*)d_out, out_w);
}